// Round 1
// 238.940 us; speedup vs baseline: 1.2498x; 1.2498x over previous
//
#include <hip/hip_runtime.h>
#include <hip/hip_bf16.h>

#define BATCH 2
#define SEQ   2048
#define CH    1024
#define NH    16
#define HD    64
#define BHN   (BATCH*NH)   /* 32 */
#define SD    (SEQ*HD)     /* 131072 */

typedef short v8s __attribute__((ext_vector_type(8)));
typedef short v4s __attribute__((ext_vector_type(4)));
typedef float v4f __attribute__((ext_vector_type(4)));

__device__ __forceinline__ short f2bf(float f) {
    unsigned u = __float_as_uint(f);
    u += 0x7fff + ((u >> 16) & 1);   // RNE; finite inputs
    return (short)(u >> 16);
}

// packed RNE: returns (bf16(a) | bf16(b)<<16) via v_cvt_pk_bf16_f32
__device__ __forceinline__ unsigned pk2bf(float a, float b) {
    __hip_bfloat162 h = __float22bfloat162_rn(make_float2(a, b));
    unsigned u;
    __builtin_memcpy(&u, &h, 4);
    return u;
}

__device__ __forceinline__ void gl_lds16(const short* g, short* l) {
    __builtin_amdgcn_global_load_lds(
        (const __attribute__((address_space(1))) void*)g,
        (__attribute__((address_space(3))) void*)l, 16, 0, 0);
}

// ---------------------------------------------------------------------------
// Fused fp32 -> bf16 cast for src / Wq / Wk / Wv / rel_k_table.
// ---------------------------------------------------------------------------
__global__ __launch_bounds__(256) void cast_all_kernel(
    const float* __restrict__ src, const float* __restrict__ wq,
    const float* __restrict__ wk, const float* __restrict__ wv,
    const float* __restrict__ rel,
    short* __restrict__ xb, short* __restrict__ wqb,
    short* __restrict__ wkb, short* __restrict__ wvb,
    short* __restrict__ relb)
{
    const int z = blockIdx.z;
    const float* s; short* d; int n4;
    switch (z) {
        case 0: s = src; d = xb;   n4 = 1048576; break;  // 4Mi elems
        case 1: s = wq;  d = wqb;  n4 = 262144;  break;
        case 2: s = wk;  d = wkb;  n4 = 262144;  break;
        case 3: s = wv;  d = wvb;  n4 = 262144;  break;
        default: s = rel; d = relb; n4 = 65520;  break;  // 4095*64/4
    }
    for (int i = blockIdx.x * 256 + threadIdx.x; i < n4; i += gridDim.x * 256) {
        float4 v = ((const float4*)s)[i];
        v4s o; o.x = f2bf(v.x); o.y = f2bf(v.y); o.z = f2bf(v.z); o.w = f2bf(v.w);
        ((v4s*)d)[i] = o;
    }
}

// ---------------------------------------------------------------------------
// bf16 MFMA projection GEMM: out[m][n] = sum_k X[m][k]*W[n][k] + bias[n]
// M=4096, N=K=1024. 128x128 tile, BK=32, global_load_lds width 16.
// z==0 (Q): result pre-scaled by 0.125 (exact in bf16, exponent shift).
// ---------------------------------------------------------------------------
__global__ __launch_bounds__(256, 3) void proj_mfma_kernel(
    const short* __restrict__ Xb,
    const short* __restrict__ Wqb, const short* __restrict__ Wkb,
    const short* __restrict__ Wvb,
    const float* __restrict__ bq, const float* __restrict__ bk,
    const float* __restrict__ bv,
    short* __restrict__ qo, short* __restrict__ ko, short* __restrict__ vo)
{
    const int z = blockIdx.z;
    const short* W    = (z == 0) ? Wqb : (z == 1) ? Wkb : Wvb;
    const float* bias = (z == 0) ? bq  : (z == 1) ? bk  : bv;
    short*       out  = (z == 0) ? qo  : (z == 1) ? ko  : vo;
    const float  osc  = (z == 0) ? 0.125f : 1.0f;

    const int m0 = blockIdx.y * 128;
    const int n0 = blockIdx.x * 128;
    const int tid  = threadIdx.x;
    const int w    = tid >> 6;
    const int lane = tid & 63;
    const int l15  = lane & 15;
    const int quad = lane >> 4;
    const int wm = w & 1, wn = w >> 1;

    __shared__ short Al[128 * 32];   // [row][k], stride 32 (no pad: glds)
    __shared__ short Bl[128 * 32];

    v4f acc[4][4];
#pragma unroll
    for (int i = 0; i < 4; i++)
#pragma unroll
        for (int j = 0; j < 4; j++) acc[i][j] = (v4f)(0.f);

    const int lr = lane >> 2;          // 0..15 row-within-slab
    const int lc = (lane & 3) * 8;     // k-offset

    for (int k0 = 0; k0 < 1024; k0 += 32) {
        __syncthreads();
#pragma unroll
        for (int l = 0; l < 2; l++) {
            const int slab = w * 32 + l * 16;
            gl_lds16(Xb + (size_t)(m0 + slab + lr) * 1024 + k0 + lc,
                     &Al[slab * 32]);
            gl_lds16(W + (size_t)(n0 + slab + lr) * 1024 + k0 + lc,
                     &Bl[slab * 32]);
        }
        __syncthreads();
        v8s af[4], bf[4];
#pragma unroll
        for (int mt = 0; mt < 4; mt++)
            af[mt] = *(const v8s*)&Al[(wm * 64 + mt * 16 + l15) * 32 + quad * 8];
#pragma unroll
        for (int nt = 0; nt < 4; nt++)
            bf[nt] = *(const v8s*)&Bl[(wn * 64 + nt * 16 + l15) * 32 + quad * 8];
#pragma unroll
        for (int mt = 0; mt < 4; mt++)
#pragma unroll
            for (int nt = 0; nt < 4; nt++)
                acc[mt][nt] = __builtin_amdgcn_mfma_f32_16x16x32_bf16(
                    af[mt], bf[nt], acc[mt][nt], 0, 0, 0);
    }

    float bv4[4];
#pragma unroll
    for (int nt = 0; nt < 4; nt++)
        bv4[nt] = bias[n0 + wn * 64 + nt * 16 + l15];
#pragma unroll
    for (int mt = 0; mt < 4; mt++)
#pragma unroll
        for (int rg = 0; rg < 4; rg++) {
            const int row = m0 + wm * 64 + mt * 16 + quad * 4 + rg;
#pragma unroll
            for (int nt = 0; nt < 4; nt++)
                out[(size_t)row * 1024 + n0 + wn * 64 + nt * 16 + l15] =
                    f2bf((acc[mt][nt][rg] + bv4[nt]) * osc);
        }
}

// ---------------------------------------------------------------------------
// V transpose per (b,h): vt[bh][d][.] = v[bh][.][d].  64x64 LDS tiles.
// R11: columns within each 64-wide t-group are stored PERMUTED:
//   position p holds t(p) = (p>>2) + 16*(p&3)   (inverse: p = (t&15)*4 + t>>4)
// so that the attention kernel's P-tile can be written with packed b64
// stores (4 adjacent shorts per lane) while PV stays an exact contraction.
// ---------------------------------------------------------------------------
__global__ __launch_bounds__(256) void vtrans_kernel(
    const short* __restrict__ v, short* __restrict__ vt)
{
    const int bh = blockIdx.y;
    const int t0 = blockIdx.x * 64;
    const int r = threadIdx.x >> 3;          // 0..31
    const int c = (threadIdx.x & 7) * 8;     // 0..56

    __shared__ short T[64][72];
    *(v8s*)&T[r][c] =
        *(const v8s*)(v + (size_t)bh * SD + (size_t)(t0 + r) * HD + c);
    *(v8s*)&T[r + 32][c] =
        *(const v8s*)(v + (size_t)bh * SD + (size_t)(t0 + r + 32) * HD + c);
    __syncthreads();
    v8s o0, o1;
#pragma unroll
    for (int e = 0; e < 8; e++) {
        const int t = 2 * (threadIdx.x & 7) + (e >> 2) + 16 * (e & 3);
        o0[e] = T[t][r];
        o1[e] = T[t][r + 32];
    }
    *(v8s*)(vt + (size_t)bh * SD + (size_t)r * SEQ + t0 + c) = o0;
    *(v8s*)(vt + (size_t)bh * SD + (size_t)(r + 32) * SEQ + t0 + c) = o1;
}

// ---------------------------------------------------------------------------
// MFMA flash attention with relative-position scores (bf16 inputs; q tensor
// pre-scaled by 1/8 in the projection).
//   score[i][t] = qs[i]·k[t] + qrs[i]·rel[t-i+2047]
//
// R11 restructure (m97-style fully-async staging; all operand feeds LDS):
//  * K/V tiles staged via global_load_lds w16 into linear [64][64] LDS with
//    SOURCE-side XOR chunk swizzle (chunk ^= row&7) -> conflict-free b128
//    reads, no VGPR round-trip, loads issued right after the barrier and
//    drained by the NEXT barrier (full iteration of latency cover).
//  * rel table staged into a 256-row LDS ring (power-of-2 slot = row&255),
//    64 new rows/iter via one global_load_lds per thread; rel fragment reads
//    become ds_read_b128 -> L2 latency off the critical path.
//  * P stored t-permuted (pos = (t&15)*4 + t>>4, matching vtrans output):
//    16 ds_write_b16 -> 4 packed ds_write_b64 (v_cvt_pk_bf16_f32); Pb is
//    XOR-swizzled like K/V for conflict-free reads.
//  * s_setprio(1) around MFMA clusters (T5).
// LDS: 16K(K) + 16K(V) + 32K(rel ring) + 16K(Pb) = 80 KB -> 2 blocks/CU.
// ---------------------------------------------------------------------------
__global__ __launch_bounds__(512, 4) void attn_mfma_kernel(
    const short* __restrict__ qb, const short* __restrict__ kb,
    const short* __restrict__ vtb, const short* __restrict__ relb,
    float* __restrict__ out)
{
    const int tid  = threadIdx.x;
    const int w    = tid >> 6;               // 0..7
    const int lane = tid & 63;
    const int l15  = lane & 15;
    const int quad = lane >> 4;
    const int bh = blockIdx.y, b = bh >> 4, h = bh & 15;
    const int s0 = blockIdx.x * 128;
    const int i0 = w * 16;

    __shared__ short Kl[2][64][64];      // key tile, dbuf, XOR-swizzled
    __shared__ short Vl[2][64][64];      // V^T tile, dbuf, XOR-swizzled (+perm cols)
    __shared__ short Rl[256][64];        // rel ring, XOR-swizzled
    __shared__ short Pb[8][16][64];      // per-wave P (bf16, permuted cols, swizzled)

    // ---- loop-invariant q fragments (both views) ----
    v8s qc_f[2], qr_f[2];
#pragma unroll
    for (int kh = 0; kh < 2; kh++) {
        const int row = s0 + i0 + l15;
        qc_f[kh] = *(const v8s*)(qb + (size_t)bh * SD +
                                 (size_t)row * HD + kh * 32 + quad * 8);
        qr_f[kh] = *(const v8s*)(qb + (size_t)row * (BHN * HD) +
                                 bh * HD + kh * 32 + quad * 8);
    }

    // ---- loop-invariant gather selectors ----
    int  slv[4];
    bool elo[4];
#pragma unroll
    for (int rg = 0; rg < 4; rg++) {
        const int ii = quad * 4 + rg;
        const int e  = l15 + 15 - ii;          // [0,30]
        slv[rg] = quad * 16 + (e & 15);
        elo[rg] = (e < 16);
    }

    // ---- loop-invariant LDS read byte-offsets (XOR-swizzled; kh=1 via ^64) ----
    const int swz = (quad ^ (l15 & 7)) << 4;
    int kaddr[4];                              // K and V^T tiles share geometry
#pragma unroll
    for (int nt = 0; nt < 4; nt++) kaddr[nt] = ((nt * 16 + l15) << 7) + swz;
    const int paddr = (l15 << 7) + swz;        // Pb read (within wave's 2KB)

    // ---- rel ring read byte-offsets (slot = logical row & 255) ----
    const int Bq = 1920 - s0;                  // min logical rel row for block
    int raddr[5];
#pragma unroll
    for (int jt = 0; jt < 5; jt++) {
        const int lg = 2032 - s0 - i0 + jt * 16 + l15;   // logical row @ t0=0
        raddr[jt] = ((lg & 255) << 7) + ((quad ^ (lg & 7)) << 4);
    }

    // ---- staging geometry: 512 threads cover one 64x64 tile ----
    const int strow = tid >> 3;                            // tile row 0..63
    const int stc   = ((tid & 7) ^ (strow & 7)) * 8;       // swizzled src col
    const short* ksrc = kb  + (size_t)bh * SD + (size_t)strow * HD  + stc;
    const short* vsrc = vtb + (size_t)bh * SD + (size_t)strow * SEQ + stc;

    // ---- prologue: rel window [Bq, Bq+192) + K/V tile 0 ----
#pragma unroll
    for (int g = 0; g < 3; g++) {
        const int lr = Bq + g * 64 + strow;
        const int cr = lr < 4094 ? lr : 4094;
        gl_lds16(relb + (size_t)cr * HD + stc,
                 &Rl[(Bq + g * 64 + w * 8) & 255][0]);
    }
    gl_lds16(ksrc, &Kl[0][w * 8][0]);
    gl_lds16(vsrc, &Vl[0][w * 8][0]);

    v4f o_acc[4];
#pragma unroll
    for (int nt = 0; nt < 4; nt++) o_acc[nt] = (v4f)(0.f);
    float lpart[4] = {0.f, 0.f, 0.f, 0.f};

    int cur = 0;
    for (int t0 = 0; t0 < SEQ; t0 += 64, cur ^= 1) {
        __syncthreads();   // buf[cur]+rel staged (vmcnt drained); prior reads done

        // ---- issue next tile's async staging (drained by NEXT barrier) ----
        {
            const int tn = (t0 + 64 < SEQ) ? t0 + 64 : 0;
            gl_lds16(ksrc + (size_t)tn * HD, &Kl[cur ^ 1][w * 8][0]);
            gl_lds16(vsrc + tn,              &Vl[cur ^ 1][w * 8][0]);
            const int lr = Bq + t0 + 192 + strow;
            const int cr = lr < 4094 ? lr : 4094;
            gl_lds16(relb + (size_t)cr * HD + stc,
                     &Rl[(Bq + t0 + 192 + w * 8) & 255][0]);
        }

        v4f cacc[4], racc[5];
#pragma unroll
        for (int nt = 0; nt < 4; nt++) cacc[nt] = (v4f)(0.f);
#pragma unroll
        for (int jt = 0; jt < 5; jt++) racc[jt] = (v4f)(0.f);

        const char* kbase = (const char*)Kl + cur * 8192;
        const char* vbase = (const char*)Vl + cur * 8192;
        const char* rbase = (const char*)Rl;

#pragma unroll
        for (int kh = 0; kh < 2; kh++) {
            const int x = kh << 6;             // ^64: flips chunk bit2 (= +32 cols)
            v8s kf[4], rfj[5];
#pragma unroll
            for (int nt = 0; nt < 4; nt++)
                kf[nt] = *(const v8s*)(kbase + (kaddr[nt] ^ x));
#pragma unroll
            for (int jt = 0; jt < 5; jt++)
                rfj[jt] = *(const v8s*)(rbase + (raddr[jt] ^ x));
            __builtin_amdgcn_s_setprio(1);
#pragma unroll
            for (int nt = 0; nt < 4; nt++)
                cacc[nt] = __builtin_amdgcn_mfma_f32_16x16x32_bf16(
                    qc_f[kh], kf[nt], cacc[nt], 0, 0, 0);
#pragma unroll
            for (int jt = 0; jt < 5; jt++)
                racc[jt] = __builtin_amdgcn_mfma_f32_16x16x32_bf16(
                    qr_f[kh], rfj[jt], racc[jt], 0, 0, 0);
            __builtin_amdgcn_s_setprio(0);
        }
        // advance rel ring pointers (+64 rows, wrap at 256)
#pragma unroll
        for (int jt = 0; jt < 5; jt++) raddr[jt] = (raddr[jt] + 8192) & 32767;

        // ---- phase 1: pack (v_cvt_pk_bf16) + ALL 12 bpermutes ----
        unsigned g01[4], g23[4], g4v[4];
#pragma unroll
        for (int rg = 0; rg < 4; rg++) {
            unsigned p01 = pk2bf(racc[0][rg], racc[1][rg]);
            unsigned p23 = pk2bf(racc[2][rg], racc[3][rg]);
            unsigned p4  = (unsigned)(unsigned short)f2bf(racc[4][rg]);
            g01[rg] = (unsigned)__shfl((int)p01, slv[rg]);
            g23[rg] = (unsigned)__shfl((int)p23, slv[rg]);
            g4v[rg] = (unsigned)__shfl((int)p4,  slv[rg]);
        }
        // ---- phase 2: selects + exps; packed b64 Pb writes ----
#pragma unroll
        for (int rg = 0; rg < 4; rg++) {
            const int ii = quad * 4 + rg;
            const unsigned a01 = g01[rg], a23 = g23[rg], a4 = g4v[rg];
            unsigned pb0 = elo[rg] ? (a01 << 16) : (a01 & 0xffff0000u);
            unsigned pb1 = elo[rg] ? (a01 & 0xffff0000u) : (a23 << 16);
            unsigned pb2 = elo[rg] ? (a23 << 16) : (a23 & 0xffff0000u);
            unsigned pb3 = elo[rg] ? (a23 & 0xffff0000u) : (a4  << 16);
            float p0 = __expf(cacc[0][rg] + __uint_as_float(pb0));
            float p1 = __expf(cacc[1][rg] + __uint_as_float(pb1));
            float p2 = __expf(cacc[2][rg] + __uint_as_float(pb2));
            float p3 = __expf(cacc[3][rg] + __uint_as_float(pb3));
            lpart[rg] += (p0 + p1) + (p2 + p3);
            // positions 4*l15..4*l15+3 of row ii hold cols l15+{0,16,32,48}
            char* pw = (char*)Pb + w * 2048 + ii * 128 +
                       ((((l15 >> 1) ^ (ii & 7)) << 4) + ((l15 & 1) << 3));
            *(uint2*)pw = make_uint2(pk2bf(p0, p1), pk2bf(p2, p3));
        }

        // ---- PV GEMM (P cols and V^T cols identically permuted) ----
        const char* pbase = (const char*)Pb + w * 2048;
#pragma unroll
        for (int kh = 0; kh < 2; kh++) {
            const int x = kh << 6;
            v8s pa = *(const v8s*)(pbase + (paddr ^ x));
            __builtin_amdgcn_s_setprio(1);
#pragma unroll
            for (int nt = 0; nt < 4; nt++) {
                v8s vf = *(const v8s*)(vbase + (kaddr[nt] ^ x));
                o_acc[nt] = __builtin_amdgcn_mfma_f32_16x16x32_bf16(
                    pa, vf, o_acc[nt], 0, 0, 0);
            }
            __builtin_amdgcn_s_setprio(0);
        }
    }

    // ---- epilogue: one row-sum reduction, then normalized store ----
#pragma unroll
    for (int rg = 0; rg < 4; rg++) {
        float rs = lpart[rg];
#pragma unroll
        for (int off = 1; off < 16; off <<= 1)
            rs += __shfl_xor(rs, off);
        const float inv = 1.f / rs;
        const int row = s0 + i0 + quad * 4 + rg;
        const size_t base = ((size_t)b * SEQ + row) * CH + h * HD;
#pragma unroll
        for (int nt = 0; nt < 4; nt++)
            out[base + nt * 16 + l15] = o_acc[nt][rg] * inv;
    }
}

// ---------------------------------------------------------------------------
extern "C" void kernel_launch(void* const* d_in, const int* in_sizes, int n_in,
                              void* d_out, int out_size, void* d_ws, size_t ws_size,
                              hipStream_t stream)
{
    const float* src  = (const float*)d_in[0];
    const float* Wq   = (const float*)d_in[1];
    const float* bq   = (const float*)d_in[2];
    const float* Wk   = (const float*)d_in[3];
    const float* bk   = (const float*)d_in[4];
    const float* Wv   = (const float*)d_in[5];
    const float* bv   = (const float*)d_in[6];
    const float* relk = (const float*)d_in[7];
    float* out = (float*)d_out;

    const size_t nQKV = (size_t)BATCH * SEQ * CH;      // 4 Mi elements
    const size_t nW   = (size_t)CH * CH;               // 1 Mi
    short* qb   = (short*)d_ws;
    short* kb   = qb + nQKV;
    short* vb   = kb + nQKV;
    short* vtb  = vb + nQKV;
    short* xb   = vtb + nQKV;
    short* wqb  = xb + nQKV;
    short* wkb  = wqb + nW;
    short* wvb  = wkb + nW;
    short* relb = wvb + nW;                            // 4095*64 bf16

    cast_all_kernel<<<dim3(512, 1, 5), 256, 0, stream>>>(
        src, Wq, Wk, Wv, relk, xb, wqb, wkb, wvb, relb);

    dim3 gProj(1024 / 128, 4096 / 128, 3);             // (8, 32, 3)
    proj_mfma_kernel<<<gProj, 256, 0, stream>>>(
        xb, wqb, wkb, wvb, bq, bk, bv, qb, kb, vb);

    dim3 gVt(SEQ / 64, BHN);                           // (32, 32)
    vtrans_kernel<<<gVt, 256, 0, stream>>>(vb, vtb);

    dim3 gAttn(SEQ / 128, BHN);                        // (16, 32)
    attn_mfma_kernel<<<gAttn, 512, 0, stream>>>(qb, kb, vtb, relb, out);
}

// Round 2
// 238.174 us; speedup vs baseline: 1.2538x; 1.0032x over previous
//
#include <hip/hip_runtime.h>
#include <hip/hip_bf16.h>

#define BATCH 2
#define SEQ   2048
#define CH    1024
#define NH    16
#define HD    64
#define BHN   (BATCH*NH)   /* 32 */
#define SD    (SEQ*HD)     /* 131072 */

typedef short v8s __attribute__((ext_vector_type(8)));
typedef short v4s __attribute__((ext_vector_type(4)));
typedef float v4f __attribute__((ext_vector_type(4)));

__device__ __forceinline__ short f2bf(float f) {
    unsigned u = __float_as_uint(f);
    u += 0x7fff + ((u >> 16) & 1);   // RNE; finite inputs
    return (short)(u >> 16);
}

// packed RNE: returns (bf16(a) | bf16(b)<<16) via v_cvt_pk_bf16_f32
__device__ __forceinline__ unsigned pk2bf(float a, float b) {
    __hip_bfloat162 h = __float22bfloat162_rn(make_float2(a, b));
    unsigned u;
    __builtin_memcpy(&u, &h, 4);
    return u;
}

// v_exp_f32 IS exp2 on AMDGCN (scores are pre-scaled by log2e in proj)
__device__ __forceinline__ float ex2(float x) {
    float r; asm("v_exp_f32 %0, %1" : "=v"(r) : "v"(x)); return r;
}

#if __has_builtin(__builtin_amdgcn_perm)
#define PERMB(a, b, s) __builtin_amdgcn_perm((a), (b), (s))
#else
__device__ __forceinline__ unsigned PERMB(unsigned a, unsigned b, unsigned s) {
    unsigned r = 0;
#pragma unroll
    for (int i = 0; i < 4; i++) {
        unsigned sb = (s >> (8 * i)) & 0xff, byte;
        if (sb >= 12) byte = (sb == 12) ? 0u : 0xffu;
        else if (sb < 4) byte = (b >> (8 * sb)) & 0xff;
        else byte = (a >> (8 * (sb - 4))) & 0xff;
        r |= byte << (8 * i);
    }
    return r;
}
#endif

__device__ __forceinline__ void gl_lds16(const short* g, short* l) {
    __builtin_amdgcn_global_load_lds(
        (const __attribute__((address_space(1))) void*)g,
        (__attribute__((address_space(3))) void*)l, 16, 0, 0);
}

// ---------------------------------------------------------------------------
// Fused fp32 -> bf16 cast for src / Wq / Wk / Wv / rel_k_table.
// ---------------------------------------------------------------------------
__global__ __launch_bounds__(256) void cast_all_kernel(
    const float* __restrict__ src, const float* __restrict__ wq,
    const float* __restrict__ wk, const float* __restrict__ wv,
    const float* __restrict__ rel,
    short* __restrict__ xb, short* __restrict__ wqb,
    short* __restrict__ wkb, short* __restrict__ wvb,
    short* __restrict__ relb)
{
    const int z = blockIdx.z;
    const float* s; short* d; int n4;
    switch (z) {
        case 0: s = src; d = xb;   n4 = 1048576; break;  // 4Mi elems
        case 1: s = wq;  d = wqb;  n4 = 262144;  break;
        case 2: s = wk;  d = wkb;  n4 = 262144;  break;
        case 3: s = wv;  d = wvb;  n4 = 262144;  break;
        default: s = rel; d = relb; n4 = 65520;  break;  // 4095*64/4
    }
    for (int i = blockIdx.x * 256 + threadIdx.x; i < n4; i += gridDim.x * 256) {
        float4 v = ((const float4*)s)[i];
        v4s o; o.x = f2bf(v.x); o.y = f2bf(v.y); o.z = f2bf(v.z); o.w = f2bf(v.w);
        ((v4s*)d)[i] = o;
    }
}

// ---------------------------------------------------------------------------
// bf16 MFMA projection GEMM: out[m][n] = sum_k X[m][k]*W[n][k] + bias[n]
// M=4096, N=K=1024. 128x128 tile, BK=32, global_load_lds width 16.
// z==0 (Q): result pre-scaled by 0.125*log2e (attn uses raw exp2).
// Grid is (m-panels, n-panels, z) so linear%8 == m-panel%8: each XCD keeps
// its 4 A-panels L2-resident across all 8 n-blocks.
// ---------------------------------------------------------------------------
__global__ __launch_bounds__(256, 3) void proj_mfma_kernel(
    const short* __restrict__ Xb,
    const short* __restrict__ Wqb, const short* __restrict__ Wkb,
    const short* __restrict__ Wvb,
    const float* __restrict__ bq, const float* __restrict__ bk,
    const float* __restrict__ bv,
    short* __restrict__ qo, short* __restrict__ ko, short* __restrict__ vo)
{
    const int z = blockIdx.z;
    const short* W    = (z == 0) ? Wqb : (z == 1) ? Wkb : Wvb;
    const float* bias = (z == 0) ? bq  : (z == 1) ? bk  : bv;
    short*       out  = (z == 0) ? qo  : (z == 1) ? ko  : vo;
    const float  osc  = (z == 0) ? 0.125f * 1.44269504088896f : 1.0f;

    const int m0 = blockIdx.x * 128;
    const int n0 = blockIdx.y * 128;
    const int tid  = threadIdx.x;
    const int w    = tid >> 6;
    const int lane = tid & 63;
    const int l15  = lane & 15;
    const int quad = lane >> 4;
    const int wm = w & 1, wn = w >> 1;

    __shared__ short Al[128 * 32];   // [row][k], stride 32 (no pad: glds)
    __shared__ short Bl[128 * 32];

    v4f acc[4][4];
#pragma unroll
    for (int i = 0; i < 4; i++)
#pragma unroll
        for (int j = 0; j < 4; j++) acc[i][j] = (v4f)(0.f);

    const int lr = lane >> 2;          // 0..15 row-within-slab
    const int lc = (lane & 3) * 8;     // k-offset

    for (int k0 = 0; k0 < 1024; k0 += 32) {
        __syncthreads();
#pragma unroll
        for (int l = 0; l < 2; l++) {
            const int slab = w * 32 + l * 16;
            gl_lds16(Xb + (size_t)(m0 + slab + lr) * 1024 + k0 + lc,
                     &Al[slab * 32]);
            gl_lds16(W + (size_t)(n0 + slab + lr) * 1024 + k0 + lc,
                     &Bl[slab * 32]);
        }
        __syncthreads();
        v8s af[4], bf[4];
#pragma unroll
        for (int mt = 0; mt < 4; mt++)
            af[mt] = *(const v8s*)&Al[(wm * 64 + mt * 16 + l15) * 32 + quad * 8];
#pragma unroll
        for (int nt = 0; nt < 4; nt++)
            bf[nt] = *(const v8s*)&Bl[(wn * 64 + nt * 16 + l15) * 32 + quad * 8];
#pragma unroll
        for (int mt = 0; mt < 4; mt++)
#pragma unroll
            for (int nt = 0; nt < 4; nt++)
                acc[mt][nt] = __builtin_amdgcn_mfma_f32_16x16x32_bf16(
                    af[mt], bf[nt], acc[mt][nt], 0, 0, 0);
    }

    float bv4[4];
#pragma unroll
    for (int nt = 0; nt < 4; nt++)
        bv4[nt] = bias[n0 + wn * 64 + nt * 16 + l15];
#pragma unroll
    for (int mt = 0; mt < 4; mt++)
#pragma unroll
        for (int rg = 0; rg < 4; rg++) {
            const int row = m0 + wm * 64 + mt * 16 + quad * 4 + rg;
#pragma unroll
            for (int nt = 0; nt < 4; nt++)
                out[(size_t)row * 1024 + n0 + wn * 64 + nt * 16 + l15] =
                    f2bf((acc[mt][nt][rg] + bv4[nt]) * osc);
        }
}

// ---------------------------------------------------------------------------
// V transpose per (b,h): vt[bh][d][.] = v[bh][.][d].  64x64 LDS tiles.
// Columns within each 64-wide t-group are stored PERMUTED:
//   position p holds t(p) = (p>>2) + 16*(p&3)   (inverse: p = (t&15)*4 + t>>4)
// so the attention kernel's P-tile can be written with packed b64 stores.
// ---------------------------------------------------------------------------
__global__ __launch_bounds__(256) void vtrans_kernel(
    const short* __restrict__ v, short* __restrict__ vt)
{
    const int bh = blockIdx.y;
    const int t0 = blockIdx.x * 64;
    const int r = threadIdx.x >> 3;          // 0..31
    const int c = (threadIdx.x & 7) * 8;     // 0..56

    __shared__ short T[64][72];
    *(v8s*)&T[r][c] =
        *(const v8s*)(v + (size_t)bh * SD + (size_t)(t0 + r) * HD + c);
    *(v8s*)&T[r + 32][c] =
        *(const v8s*)(v + (size_t)bh * SD + (size_t)(t0 + r + 32) * HD + c);
    __syncthreads();
    v8s o0, o1;
#pragma unroll
    for (int e = 0; e < 8; e++) {
        const int t = 2 * (threadIdx.x & 7) + (e >> 2) + 16 * (e & 3);
        o0[e] = T[t][r];
        o1[e] = T[t][r + 32];
    }
    *(v8s*)(vt + (size_t)bh * SD + (size_t)r * SEQ + t0 + c) = o0;
    *(v8s*)(vt + (size_t)bh * SD + (size_t)(r + 32) * SEQ + t0 + c) = o1;
}

// ---------------------------------------------------------------------------
// MFMA flash attention with relative-position scores (bf16 inputs; q tensor
// pre-scaled by log2e/8 in the projection; probabilities via raw v_exp_f32).
//   score[i][t]*log2e = qs[i]·k[t] + qrs[i]·rel[t-i+2047]
//
// R12 (VALU diet on the R11 structure):
//  * skew-gather selects via v_perm_b32 with loop-invariant selectors
//    (4 instrs/rg instead of ~12)
//  * exp2 direct (log2e folded into Q), raw v_exp_f32
//  * both-kh LDS read offsets, byte-ready bpermute indices, Pb write offsets
//    all precomputed (VGPR headroom: 64 -> ~110, still 4 waves/SIMD)
//  * carried staging pointers (no per-iter 64-bit address rebuild); final
//    dummy stages land harmlessly in adjacent workspace buffers
//  * grid is (bh, s0): linear%8 == bh%8 -> all 16 s0-blocks of one bh on one
//    XCD, per-XCD working set ~4MB == L2
// LDS: 16K(K) + 16K(V) + 32K(rel ring) + 16K(Pb) = 80 KB -> 2 blocks/CU.
// ---------------------------------------------------------------------------
__global__ __launch_bounds__(512, 4) void attn_mfma_kernel(
    const short* __restrict__ qb, const short* __restrict__ kb,
    const short* __restrict__ vtb, const short* __restrict__ relb,
    float* __restrict__ out)
{
    const int tid  = threadIdx.x;
    const int w    = tid >> 6;               // 0..7
    const int lane = tid & 63;
    const int l15  = lane & 15;
    const int quad = lane >> 4;
    const int bh = blockIdx.x, b = bh >> 4, h = bh & 15;
    const int s0 = blockIdx.y * 128;
    const int i0 = w * 16;

    __shared__ short Kl[2][64][64];      // key tile, dbuf, XOR-swizzled
    __shared__ short Vl[2][64][64];      // V^T tile, dbuf, XOR-swizzled (+perm cols)
    __shared__ short Rl[256][64];        // rel ring, XOR-swizzled
    __shared__ short Pb[8][16][64];      // per-wave P (bf16, permuted cols, swizzled)

    // ---- loop-invariant q fragments (both views) ----
    v8s qc_f[2], qr_f[2];
#pragma unroll
    for (int kh = 0; kh < 2; kh++) {
        const int row = s0 + i0 + l15;
        qc_f[kh] = *(const v8s*)(qb + (size_t)bh * SD +
                                 (size_t)row * HD + kh * 32 + quad * 8);
        qr_f[kh] = *(const v8s*)(qb + (size_t)row * (BHN * HD) +
                                 bh * HD + kh * 32 + quad * 8);
    }

    // ---- loop-invariant gather selectors (v_perm; 0x0c = zero byte) ----
    int      slv4[4];
    unsigned selA[4], selB[4], pwoff[4];
#pragma unroll
    for (int rg = 0; rg < 4; rg++) {
        const int ii = quad * 4 + rg;
        const int e  = l15 + 15 - ii;          // [0,30]
        const bool lo = (e < 16);
        slv4[rg] = (quad * 16 + (e & 15)) << 2;
        selA[rg] = lo ? 0x05040c0cu : 0x07060c0cu;   // lo16<<16 : hi16
        selB[rg] = lo ? 0x07060c0cu : 0x01000c0cu;   // S0 hi16 : S1 lo16<<16
        pwoff[rg] = (unsigned)(w * 2048 + ii * 128 +
                    ((((l15 >> 1) ^ (ii & 7)) << 4) + ((l15 & 1) << 3)));
    }

    // ---- loop-invariant LDS read byte-offsets, both kh variants ----
    const int swz = (quad ^ (l15 & 7)) << 4;
    int kaddr[2][4], paddr[2];
#pragma unroll
    for (int kh = 0; kh < 2; kh++) {
        const int x = kh << 6;
#pragma unroll
        for (int nt = 0; nt < 4; nt++)
            kaddr[kh][nt] = (((nt * 16 + l15) << 7) + swz) ^ x;
        paddr[kh] = ((l15 << 7) + swz) ^ x;
    }

    // ---- rel ring read byte-offsets (slot = logical row & 255) ----
    const int Bq = 1920 - s0;                  // min logical rel row for block
    int raddr[5];
#pragma unroll
    for (int jt = 0; jt < 5; jt++) {
        const int lg = 2032 - s0 - i0 + jt * 16 + l15;   // logical row @ t0=0
        raddr[jt] = ((lg & 255) << 7) + ((quad ^ (lg & 7)) << 4);
    }

    // ---- staging geometry: 512 threads cover one 64x64 tile ----
    const int strow = tid >> 3;                            // tile row 0..63
    const int stc   = ((tid & 7) ^ (strow & 7)) * 8;       // swizzled src col
    const short* ksrc = kb  + (size_t)bh * SD + (size_t)strow * HD  + stc;
    const short* vsrc = vtb + (size_t)bh * SD + (size_t)strow * SEQ + stc;

    // ---- prologue: rel window [Bq, Bq+192) + K/V tile 0 ----
#pragma unroll
    for (int g = 0; g < 3; g++) {
        const int lr2 = Bq + g * 64 + strow;
        const int cr = lr2 < 4094 ? lr2 : 4094;
        gl_lds16(relb + (size_t)cr * HD + stc,
                 &Rl[(Bq + g * 64 + w * 8) & 255][0]);
    }
    gl_lds16(ksrc, &Kl[0][w * 8][0]);
    gl_lds16(vsrc, &Vl[0][w * 8][0]);

    // ---- carried staging pointers ----
    const short* kp = ksrc + 4096;             // tile 1 (64 keys * HD)
    const short* vp = vsrc + 64;
    const char*  relbp = (const char*)relb + stc * 2;
    unsigned roff = (unsigned)(Bq + 192 + strow) * 128;  // byte row offset
    const unsigned ROMAX = 4094u * 128;
    unsigned rlds = (unsigned)((Bq + 192 + w * 8) & 255) << 7;

    v4f o_acc[4];
#pragma unroll
    for (int nt = 0; nt < 4; nt++) o_acc[nt] = (v4f)(0.f);
    float lpart[4] = {0.f, 0.f, 0.f, 0.f};

    int cur = 0;
    for (int t0 = 0; t0 < SEQ; t0 += 64, cur ^= 1) {
        __syncthreads();   // buf[cur]+rel staged (vmcnt drained); prior reads done

        // ---- issue next tile's async staging (drained by NEXT barrier) ----
        {
            short* kd = &Kl[0][w * 8][0];
            short* vd = &Vl[0][w * 8][0];
            const int nb = (cur ^ 1) << 12;    // shorts
            gl_lds16(kp, kd + nb);
            gl_lds16(vp, vd + nb);
            unsigned rc = roff < ROMAX ? roff : ROMAX;
            gl_lds16((const short*)(relbp + rc), (short*)((char*)Rl + rlds));
        }
        kp += 4096; vp += 64; roff += 8192;
        rlds = (rlds + 8192) & 32767;

        v4f cacc[4], racc[5];
#pragma unroll
        for (int nt = 0; nt < 4; nt++) cacc[nt] = (v4f)(0.f);
#pragma unroll
        for (int jt = 0; jt < 5; jt++) racc[jt] = (v4f)(0.f);

        const char* kbase = (const char*)Kl + cur * 8192;
        const char* vbase = (const char*)Vl + cur * 8192;
        const char* rbase = (const char*)Rl;

#pragma unroll
        for (int kh = 0; kh < 2; kh++) {
            v8s kf[4], rfj[5];
#pragma unroll
            for (int nt = 0; nt < 4; nt++)
                kf[nt] = *(const v8s*)(kbase + kaddr[kh][nt]);
#pragma unroll
            for (int jt = 0; jt < 5; jt++)
                rfj[jt] = *(const v8s*)(rbase + (raddr[jt] ^ (kh << 6)));
            __builtin_amdgcn_s_setprio(1);
#pragma unroll
            for (int nt = 0; nt < 4; nt++)
                cacc[nt] = __builtin_amdgcn_mfma_f32_16x16x32_bf16(
                    qc_f[kh], kf[nt], cacc[nt], 0, 0, 0);
#pragma unroll
            for (int jt = 0; jt < 5; jt++)
                racc[jt] = __builtin_amdgcn_mfma_f32_16x16x32_bf16(
                    qr_f[kh], rfj[jt], racc[jt], 0, 0, 0);
            __builtin_amdgcn_s_setprio(0);
        }
        // advance rel ring pointers (+64 rows, wrap at 256)
#pragma unroll
        for (int jt = 0; jt < 5; jt++) raddr[jt] = (raddr[jt] + 8192) & 32767;

        // ---- phase 1: pack (v_cvt_pk_bf16) + ALL 12 bpermutes ----
        unsigned g01[4], g23[4], g4v[4];
#pragma unroll
        for (int rg = 0; rg < 4; rg++) {
            unsigned p01 = pk2bf(racc[0][rg], racc[1][rg]);
            unsigned p23 = pk2bf(racc[2][rg], racc[3][rg]);
            unsigned p4  = pk2bf(racc[4][rg], racc[4][rg]);
            g01[rg] = (unsigned)__builtin_amdgcn_ds_bpermute(slv4[rg], (int)p01);
            g23[rg] = (unsigned)__builtin_amdgcn_ds_bpermute(slv4[rg], (int)p23);
            g4v[rg] = (unsigned)__builtin_amdgcn_ds_bpermute(slv4[rg], (int)p4);
        }
        // ---- phase 2: v_perm skew-selects + exp2; packed b64 Pb writes ----
#pragma unroll
        for (int rg = 0; rg < 4; rg++) {
            const unsigned a01 = g01[rg], a23 = g23[rg], a4 = g4v[rg];
            unsigned pb0 = PERMB(a01, a01, selA[rg]);
            unsigned pb1 = PERMB(a01, a23, selB[rg]);
            unsigned pb2 = PERMB(a23, a23, selA[rg]);
            unsigned pb3 = PERMB(a23, a4,  selB[rg]);
            float p0 = ex2(cacc[0][rg] + __uint_as_float(pb0));
            float p1 = ex2(cacc[1][rg] + __uint_as_float(pb1));
            float p2 = ex2(cacc[2][rg] + __uint_as_float(pb2));
            float p3 = ex2(cacc[3][rg] + __uint_as_float(pb3));
            lpart[rg] += (p0 + p1) + (p2 + p3);
            *(uint2*)((char*)Pb + pwoff[rg]) =
                make_uint2(pk2bf(p0, p1), pk2bf(p2, p3));
        }

        // ---- PV GEMM (P cols and V^T cols identically permuted) ----
        const char* pbase = (const char*)Pb + w * 2048;
#pragma unroll
        for (int kh = 0; kh < 2; kh++) {
            v8s pa = *(const v8s*)(pbase + paddr[kh]);
            __builtin_amdgcn_s_setprio(1);
#pragma unroll
            for (int nt = 0; nt < 4; nt++) {
                v8s vf = *(const v8s*)(vbase + kaddr[kh][nt]);
                o_acc[nt] = __builtin_amdgcn_mfma_f32_16x16x32_bf16(
                    pa, vf, o_acc[nt], 0, 0, 0);
            }
            __builtin_amdgcn_s_setprio(0);
        }
    }

    // ---- epilogue: one row-sum reduction, then normalized store ----
#pragma unroll
    for (int rg = 0; rg < 4; rg++) {
        float rs = lpart[rg];
#pragma unroll
        for (int off = 1; off < 16; off <<= 1)
            rs += __shfl_xor(rs, off);
        const float inv = 1.f / rs;
        const int row = s0 + i0 + quad * 4 + rg;
        const size_t base = ((size_t)b * SEQ + row) * CH + h * HD;
#pragma unroll
        for (int nt = 0; nt < 4; nt++)
            out[base + nt * 16 + l15] = o_acc[nt][rg] * inv;
    }
}

// ---------------------------------------------------------------------------
extern "C" void kernel_launch(void* const* d_in, const int* in_sizes, int n_in,
                              void* d_out, int out_size, void* d_ws, size_t ws_size,
                              hipStream_t stream)
{
    const float* src  = (const float*)d_in[0];
    const float* Wq   = (const float*)d_in[1];
    const float* bq   = (const float*)d_in[2];
    const float* Wk   = (const float*)d_in[3];
    const float* bk   = (const float*)d_in[4];
    const float* Wv   = (const float*)d_in[5];
    const float* bv   = (const float*)d_in[6];
    const float* relk = (const float*)d_in[7];
    float* out = (float*)d_out;

    const size_t nQKV = (size_t)BATCH * SEQ * CH;      // 4 Mi elements
    const size_t nW   = (size_t)CH * CH;               // 1 Mi
    short* qb   = (short*)d_ws;
    short* kb   = qb + nQKV;
    short* vb   = kb + nQKV;
    short* vtb  = vb + nQKV;
    short* xb   = vtb + nQKV;
    short* wqb  = xb + nQKV;
    short* wkb  = wqb + nW;
    short* wvb  = wkb + nW;
    short* relb = wvb + nW;                            // 4095*64 bf16

    cast_all_kernel<<<dim3(512, 1, 5), 256, 0, stream>>>(
        src, Wq, Wk, Wv, relk, xb, wqb, wkb, wvb, relb);

    dim3 gProj(4096 / 128, 1024 / 128, 3);             // (32, 8, 3): x = m-panel
    proj_mfma_kernel<<<gProj, 256, 0, stream>>>(
        xb, wqb, wkb, wvb, bq, bk, bv, qb, kb, vb);

    dim3 gVt(SEQ / 64, BHN);                           // (32, 32)
    vtrans_kernel<<<gVt, 256, 0, stream>>>(vb, vtb);

    dim3 gAttn(BHN, SEQ / 128);                        // (32, 16): x = bh
    attn_mfma_kernel<<<gAttn, 512, 0, stream>>>(qb, kb, vtb, relb, out);
}

// Round 3
// 209.473 us; speedup vs baseline: 1.4256x; 1.1370x over previous
//
#include <hip/hip_runtime.h>
#include <hip/hip_bf16.h>

#define BATCH 2
#define SEQ   2048
#define CH    1024
#define NH    16
#define HD    64
#define BHN   (BATCH*NH)   /* 32 */
#define SD    (SEQ*HD)     /* 131072 */

typedef short v8s __attribute__((ext_vector_type(8)));
typedef short v4s __attribute__((ext_vector_type(4)));
typedef float v4f __attribute__((ext_vector_type(4)));

__device__ __forceinline__ short f2bf(float f) {
    unsigned u = __float_as_uint(f);
    u += 0x7fff + ((u >> 16) & 1);   // RNE; finite inputs
    return (short)(u >> 16);
}

// packed RNE: returns (bf16(a) | bf16(b)<<16) via v_cvt_pk_bf16_f32
__device__ __forceinline__ unsigned pk2bf(float a, float b) {
    __hip_bfloat162 h = __float22bfloat162_rn(make_float2(a, b));
    unsigned u;
    __builtin_memcpy(&u, &h, 4);
    return u;
}

// v_exp_f32 IS exp2 on AMDGCN (scores are pre-scaled by log2e in proj)
__device__ __forceinline__ float ex2(float x) {
    float r; asm("v_exp_f32 %0, %1" : "=v"(r) : "v"(x)); return r;
}

#if __has_builtin(__builtin_amdgcn_perm)
#define PERMB(a, b, s) __builtin_amdgcn_perm((a), (b), (s))
#else
__device__ __forceinline__ unsigned PERMB(unsigned a, unsigned b, unsigned s) {
    unsigned r = 0;
#pragma unroll
    for (int i = 0; i < 4; i++) {
        unsigned sb = (s >> (8 * i)) & 0xff, byte;
        if (sb >= 12) byte = (sb == 12) ? 0u : 0xffu;
        else if (sb < 4) byte = (b >> (8 * sb)) & 0xff;
        else byte = (a >> (8 * (sb - 4))) & 0xff;
        r |= byte << (8 * i);
    }
    return r;
}
#endif

__device__ __forceinline__ void gl_lds16(const short* g, short* l) {
    __builtin_amdgcn_global_load_lds(
        (const __attribute__((address_space(1))) void*)g,
        (__attribute__((address_space(3))) void*)l, 16, 0, 0);
}

// ---------------------------------------------------------------------------
// Fused fp32 -> bf16 cast for src / Wq / Wk / Wv / rel_k_table.
// ---------------------------------------------------------------------------
__global__ __launch_bounds__(256) void cast_all_kernel(
    const float* __restrict__ src, const float* __restrict__ wq,
    const float* __restrict__ wk, const float* __restrict__ wv,
    const float* __restrict__ rel,
    short* __restrict__ xb, short* __restrict__ wqb,
    short* __restrict__ wkb, short* __restrict__ wvb,
    short* __restrict__ relb)
{
    const int z = blockIdx.z;
    const float* s; short* d; int n4;
    switch (z) {
        case 0: s = src; d = xb;   n4 = 1048576; break;  // 4Mi elems
        case 1: s = wq;  d = wqb;  n4 = 262144;  break;
        case 2: s = wk;  d = wkb;  n4 = 262144;  break;
        case 3: s = wv;  d = wvb;  n4 = 262144;  break;
        default: s = rel; d = relb; n4 = 65520;  break;  // 4095*64/4
    }
    for (int i = blockIdx.x * 256 + threadIdx.x; i < n4; i += gridDim.x * 256) {
        float4 v = ((const float4*)s)[i];
        v4s o; o.x = f2bf(v.x); o.y = f2bf(v.y); o.z = f2bf(v.z); o.w = f2bf(v.w);
        ((v4s*)d)[i] = o;
    }
}

// ---------------------------------------------------------------------------
// bf16 MFMA projection GEMM: out[m][n] = sum_k X[m][k]*W[n][k] + bias[n]
// M=4096, N=K=1024. 128x128 tile, BK=32, global_load_lds width 16.
// z==0 (Q): result pre-scaled by 0.125*log2e (attn uses raw exp2).
// Grid is (m-panels, n-panels, z): linear%8 == m-panel%8 keeps each XCD's
// A-panels L2-resident across all 8 n-blocks.
// ---------------------------------------------------------------------------
__global__ __launch_bounds__(256, 3) void proj_mfma_kernel(
    const short* __restrict__ Xb,
    const short* __restrict__ Wqb, const short* __restrict__ Wkb,
    const short* __restrict__ Wvb,
    const float* __restrict__ bq, const float* __restrict__ bk,
    const float* __restrict__ bv,
    short* __restrict__ qo, short* __restrict__ ko, short* __restrict__ vo)
{
    const int z = blockIdx.z;
    const short* W    = (z == 0) ? Wqb : (z == 1) ? Wkb : Wvb;
    const float* bias = (z == 0) ? bq  : (z == 1) ? bk  : bv;
    short*       out  = (z == 0) ? qo  : (z == 1) ? ko  : vo;
    const float  osc  = (z == 0) ? 0.125f * 1.44269504088896f : 1.0f;

    const int m0 = blockIdx.x * 128;
    const int n0 = blockIdx.y * 128;
    const int tid  = threadIdx.x;
    const int w    = tid >> 6;
    const int lane = tid & 63;
    const int l15  = lane & 15;
    const int quad = lane >> 4;
    const int wm = w & 1, wn = w >> 1;

    __shared__ short Al[128 * 32];   // [row][k], stride 32 (no pad: glds)
    __shared__ short Bl[128 * 32];

    v4f acc[4][4];
#pragma unroll
    for (int i = 0; i < 4; i++)
#pragma unroll
        for (int j = 0; j < 4; j++) acc[i][j] = (v4f)(0.f);

    const int lr = lane >> 2;          // 0..15 row-within-slab
    const int lc = (lane & 3) * 8;     // k-offset

    for (int k0 = 0; k0 < 1024; k0 += 32) {
        __syncthreads();
#pragma unroll
        for (int l = 0; l < 2; l++) {
            const int slab = w * 32 + l * 16;
            gl_lds16(Xb + (size_t)(m0 + slab + lr) * 1024 + k0 + lc,
                     &Al[slab * 32]);
            gl_lds16(W + (size_t)(n0 + slab + lr) * 1024 + k0 + lc,
                     &Bl[slab * 32]);
        }
        __syncthreads();
        v8s af[4], bf[4];
#pragma unroll
        for (int mt = 0; mt < 4; mt++)
            af[mt] = *(const v8s*)&Al[(wm * 64 + mt * 16 + l15) * 32 + quad * 8];
#pragma unroll
        for (int nt = 0; nt < 4; nt++)
            bf[nt] = *(const v8s*)&Bl[(wn * 64 + nt * 16 + l15) * 32 + quad * 8];
#pragma unroll
        for (int mt = 0; mt < 4; mt++)
#pragma unroll
            for (int nt = 0; nt < 4; nt++)
                acc[mt][nt] = __builtin_amdgcn_mfma_f32_16x16x32_bf16(
                    af[mt], bf[nt], acc[mt][nt], 0, 0, 0);
    }

    float bv4[4];
#pragma unroll
    for (int nt = 0; nt < 4; nt++)
        bv4[nt] = bias[n0 + wn * 64 + nt * 16 + l15];
#pragma unroll
    for (int mt = 0; mt < 4; mt++)
#pragma unroll
        for (int rg = 0; rg < 4; rg++) {
            const int row = m0 + wm * 64 + mt * 16 + quad * 4 + rg;
#pragma unroll
            for (int nt = 0; nt < 4; nt++)
                out[(size_t)row * 1024 + n0 + wn * 64 + nt * 16 + l15] =
                    f2bf((acc[mt][nt][rg] + bv4[nt]) * osc);
        }
}

// ---------------------------------------------------------------------------
// V transpose per (b,h): vt[bh][d][.] = v[bh][.][d].  64x64 LDS tiles.
// Columns within each 64-wide t-group are stored PERMUTED:
//   position p holds t(p) = (p>>2) + 16*(p&3)   (inverse: p = (t&15)*4 + t>>4)
// so the attention kernel's P-tile can be written with packed b64 stores.
// ---------------------------------------------------------------------------
__global__ __launch_bounds__(256) void vtrans_kernel(
    const short* __restrict__ v, short* __restrict__ vt)
{
    const int bh = blockIdx.y;
    const int t0 = blockIdx.x * 64;
    const int r = threadIdx.x >> 3;          // 0..31
    const int c = (threadIdx.x & 7) * 8;     // 0..56

    __shared__ short T[64][72];
    *(v8s*)&T[r][c] =
        *(const v8s*)(v + (size_t)bh * SD + (size_t)(t0 + r) * HD + c);
    *(v8s*)&T[r + 32][c] =
        *(const v8s*)(v + (size_t)bh * SD + (size_t)(t0 + r + 32) * HD + c);
    __syncthreads();
    v8s o0, o1;
#pragma unroll
    for (int e = 0; e < 8; e++) {
        const int t = 2 * (threadIdx.x & 7) + (e >> 2) + 16 * (e & 3);
        o0[e] = T[t][r];
        o1[e] = T[t][r + 32];
    }
    *(v8s*)(vt + (size_t)bh * SD + (size_t)r * SEQ + t0 + c) = o0;
    *(v8s*)(vt + (size_t)bh * SD + (size_t)(r + 32) * SEQ + t0 + c) = o1;
}

// ---------------------------------------------------------------------------
// MFMA flash attention with relative-position scores (bf16 inputs; q tensor
// pre-scaled by log2e/8 in the projection; probabilities via raw v_exp_f32).
//   score[i][t]*log2e = qs[i]·k[t] + qrs[i]·rel[t-i+2047]
//
// R13 (LDS-traffic diet): R12's counters showed VALUBusy -7pt with flat
// time -> LDS pipe (~72% busy: 28 b128 reads/wave/iter x 16 waves) is the
// binder, driven by 8x duplication of K/V reads across 16-row waves.
// Restructure: 4 waves x TWO 16-row m-tiles each (32 q-rows/wave):
//  * K and V fragment reads shared by both m-tiles (8 reads serve 2x rows)
//  * the two rel strips overlap -> one 6-tile strip (12 reads serve both
//    m-tiles' 20 rel MFMAs)
//  * per-wave reads 28 -> 32 b128 for 2x rows (1.75x less LDS per row)
//  * TLP halves (8 waves/CU) but each wave carries 2 independent
//    softmax/gather chains (ILP replaces TLP); launch_bounds(256,2) gives
//    256-VGPR budget so nothing spills.
// LDS: 16K(K) + 16K(V) + 32K(rel ring) + 16K(Pb) = 80 KB -> 2 blocks/CU.
// ---------------------------------------------------------------------------
__global__ __launch_bounds__(256, 2) void attn_mfma_kernel(
    const short* __restrict__ qb, const short* __restrict__ kb,
    const short* __restrict__ vtb, const short* __restrict__ relb,
    float* __restrict__ out)
{
    const int tid  = threadIdx.x;
    const int w    = tid >> 6;               // 0..3
    const int lane = tid & 63;
    const int l15  = lane & 15;
    const int quad = lane >> 4;
    const int bh = blockIdx.x, b = bh >> 4, h = bh & 15;
    const int s0 = blockIdx.y * 128;
    const int i0 = w * 32;                   // wave's 32-row slab

    __shared__ short Kl[2][64][64];      // key tile, dbuf, XOR-swizzled
    __shared__ short Vl[2][64][64];      // V^T tile, dbuf, XOR-swizzled (+perm cols)
    __shared__ short Rl[256][64];        // rel ring, XOR-swizzled
    __shared__ short Pb[4][2][16][64];   // per-wave/mt P (bf16, perm cols, swz)

    // ---- loop-invariant q fragments (both views, both m-tiles) ----
    v8s qc_f[2][2], qr_f[2][2];
#pragma unroll
    for (int mt = 0; mt < 2; mt++)
#pragma unroll
    for (int kh = 0; kh < 2; kh++) {
        const int row = s0 + i0 + mt * 16 + l15;
        qc_f[mt][kh] = *(const v8s*)(qb + (size_t)bh * SD +
                                     (size_t)row * HD + kh * 32 + quad * 8);
        qr_f[mt][kh] = *(const v8s*)(qb + (size_t)row * (BHN * HD) +
                                     bh * HD + kh * 32 + quad * 8);
    }

    // ---- loop-invariant gather selectors (v_perm; 0x0c = zero byte) ----
    int      slv4[4];
    unsigned selA[4], selB[4], pwoff[4];
#pragma unroll
    for (int rg = 0; rg < 4; rg++) {
        const int ii = quad * 4 + rg;
        const int e  = l15 + 15 - ii;          // [0,30]
        const bool lo = (e < 16);
        slv4[rg] = (quad * 16 + (e & 15)) << 2;
        selA[rg] = lo ? 0x05040c0cu : 0x07060c0cu;   // lo16<<16 : hi16
        selB[rg] = lo ? 0x07060c0cu : 0x01000c0cu;   // S0 hi16 : S1 lo16<<16
        pwoff[rg] = (unsigned)(w * 4096 + ii * 128 +
                    ((((l15 >> 1) ^ (ii & 7)) << 4) + ((l15 & 1) << 3)));
    }

    // ---- loop-invariant LDS read byte-offsets ----
    const int swz = (quad ^ (l15 & 7)) << 4;
    int kaddr[2][4];
#pragma unroll
    for (int kh = 0; kh < 2; kh++) {
        const int x = kh << 6;
#pragma unroll
        for (int nt = 0; nt < 4; nt++)
            kaddr[kh][nt] = (((nt * 16 + l15) << 7) + swz) ^ x;
    }
    const int paddr0 = (l15 << 7) + swz;       // within one 2KB Pb m-tile

    // ---- rel strip read byte-offsets (6 tiles; m1 uses 0..4, m0 uses 1..5) ----
    const int Bq = 1920 - s0;                  // min logical rel row for block
    int raddr[6];
#pragma unroll
    for (int st = 0; st < 6; st++) {
        const int lg = 2032 - s0 - i0 - 16 + st * 16 + l15;  // m1 frame @ t0=0
        raddr[st] = ((lg & 255) << 7) + ((quad ^ (lg & 7)) << 4);
    }

    // ---- staging geometry: 256 threads x2 issues cover one 64x64 tile ----
    const int strow = tid >> 3;                            // 0..31
    const int stc   = ((tid & 7) ^ (strow & 7)) * 8;       // swizzled src col
    const short* ksrc = kb  + (size_t)bh * SD + (size_t)strow * HD  + stc;
    const short* vsrc = vtb + (size_t)bh * SD + (size_t)strow * SEQ + stc;

    // ---- prologue: rel window [Bq, Bq+192) + K/V tile 0 ----
#pragma unroll
    for (int g = 0; g < 3; g++) {
        const int r0 = Bq + g * 64 + strow;
        const int ra = r0 < 4094 ? r0 : 4094;
        const int rb2 = (r0 + 32) < 4094 ? (r0 + 32) : 4094;
        const unsigned sl = (unsigned)((Bq + g * 64 + w * 8) & 255) << 7;
        gl_lds16(relb + (size_t)ra * HD + stc, (short*)((char*)Rl + sl));
        gl_lds16(relb + (size_t)rb2 * HD + stc, (short*)((char*)Rl + sl + 4096));
    }
    gl_lds16(ksrc,              &Kl[0][w * 8][0]);
    gl_lds16(ksrc + 32 * HD,    &Kl[0][32 + w * 8][0]);
    gl_lds16(vsrc,              &Vl[0][w * 8][0]);
    gl_lds16(vsrc + 32 * SEQ,   &Vl[0][32 + w * 8][0]);

    // ---- carried staging pointers ----
    const short* kp = ksrc + 4096;             // tile 1 (64 keys * HD)
    const short* vp = vsrc + 64;
    const char*  relbp = (const char*)relb + stc * 2;
    unsigned roff = (unsigned)(Bq + 192 + strow) * 128;  // byte row offset
    const unsigned ROMAX = 4094u * 128;
    unsigned rlds = (unsigned)((Bq + 192 + w * 8) & 255) << 7;

    v4f o_acc[2][4];
#pragma unroll
    for (int mt = 0; mt < 2; mt++)
#pragma unroll
        for (int nt = 0; nt < 4; nt++) o_acc[mt][nt] = (v4f)(0.f);
    float lpart[2][4] = {{0.f,0.f,0.f,0.f},{0.f,0.f,0.f,0.f}};

    int cur = 0;
    for (int t0 = 0; t0 < SEQ; t0 += 64, cur ^= 1) {
        __syncthreads();   // buf[cur]+rel staged (vmcnt drained); prior reads done

        // ---- issue next tile's async staging (drained by NEXT barrier) ----
        {
            const int nb = (cur ^ 1) << 12;    // shorts (one 8KB buffer)
            short* kd = &Kl[0][w * 8][0] + nb;
            short* vd = &Vl[0][w * 8][0] + nb;
            gl_lds16(kp,            kd);
            gl_lds16(kp + 32 * HD,  kd + 32 * 64);
            gl_lds16(vp,            vd);
            gl_lds16(vp + 32 * SEQ, vd + 32 * 64);
            unsigned rc0 = roff < ROMAX ? roff : ROMAX;
            unsigned rc1 = (roff + 4096) < ROMAX ? (roff + 4096) : ROMAX;
            gl_lds16((const short*)(relbp + rc0), (short*)((char*)Rl + rlds));
            gl_lds16((const short*)(relbp + rc1), (short*)((char*)Rl + rlds + 4096));
        }
        kp += 4096; vp += 64; roff += 8192;
        rlds = (rlds + 8192) & 32767;

        v4f cacc[2][4], racc[2][5];
#pragma unroll
        for (int mt = 0; mt < 2; mt++) {
#pragma unroll
            for (int nt = 0; nt < 4; nt++) cacc[mt][nt] = (v4f)(0.f);
#pragma unroll
            for (int jt = 0; jt < 5; jt++) racc[mt][jt] = (v4f)(0.f);
        }

        const char* kbase = (const char*)Kl + cur * 8192;
        const char* vbase = (const char*)Vl + cur * 8192;
        const char* rbase = (const char*)Rl;

#pragma unroll
        for (int kh = 0; kh < 2; kh++) {
            v8s kf[4], rfj[6];
#pragma unroll
            for (int nt = 0; nt < 4; nt++)
                kf[nt] = *(const v8s*)(kbase + kaddr[kh][nt]);
#pragma unroll
            for (int st = 0; st < 6; st++)
                rfj[st] = *(const v8s*)(rbase + (raddr[st] ^ (kh << 6)));
            __builtin_amdgcn_s_setprio(1);
#pragma unroll
            for (int mt = 0; mt < 2; mt++)
#pragma unroll
                for (int nt = 0; nt < 4; nt++)
                    cacc[mt][nt] = __builtin_amdgcn_mfma_f32_16x16x32_bf16(
                        qc_f[mt][kh], kf[nt], cacc[mt][nt], 0, 0, 0);
#pragma unroll
            for (int jt = 0; jt < 5; jt++)
                racc[0][jt] = __builtin_amdgcn_mfma_f32_16x16x32_bf16(
                    qr_f[0][kh], rfj[jt + 1], racc[0][jt], 0, 0, 0);
#pragma unroll
            for (int jt = 0; jt < 5; jt++)
                racc[1][jt] = __builtin_amdgcn_mfma_f32_16x16x32_bf16(
                    qr_f[1][kh], rfj[jt], racc[1][jt], 0, 0, 0);
            __builtin_amdgcn_s_setprio(0);
        }
        // advance rel strip (+64 rows, wrap at 256)
#pragma unroll
        for (int st = 0; st < 6; st++) raddr[st] = (raddr[st] + 8192) & 32767;

        // ---- phase 1: pack + ALL 24 bpermutes (both m-tiles) ----
        unsigned g01[2][4], g23[2][4], g4v[2][4];
#pragma unroll
        for (int mt = 0; mt < 2; mt++)
#pragma unroll
        for (int rg = 0; rg < 4; rg++) {
            unsigned p01 = pk2bf(racc[mt][0][rg], racc[mt][1][rg]);
            unsigned p23 = pk2bf(racc[mt][2][rg], racc[mt][3][rg]);
            unsigned p4  = pk2bf(racc[mt][4][rg], racc[mt][4][rg]);
            g01[mt][rg] = (unsigned)__builtin_amdgcn_ds_bpermute(slv4[rg], (int)p01);
            g23[mt][rg] = (unsigned)__builtin_amdgcn_ds_bpermute(slv4[rg], (int)p23);
            g4v[mt][rg] = (unsigned)__builtin_amdgcn_ds_bpermute(slv4[rg], (int)p4);
        }
        // ---- phase 2: v_perm skew-selects + exp2; packed b64 Pb writes ----
#pragma unroll
        for (int mt = 0; mt < 2; mt++)
#pragma unroll
        for (int rg = 0; rg < 4; rg++) {
            const unsigned a01 = g01[mt][rg], a23 = g23[mt][rg], a4 = g4v[mt][rg];
            unsigned pb0 = PERMB(a01, a01, selA[rg]);
            unsigned pb1 = PERMB(a01, a23, selB[rg]);
            unsigned pb2 = PERMB(a23, a23, selA[rg]);
            unsigned pb3 = PERMB(a23, a4,  selB[rg]);
            float p0 = ex2(cacc[mt][0][rg] + __uint_as_float(pb0));
            float p1 = ex2(cacc[mt][1][rg] + __uint_as_float(pb1));
            float p2 = ex2(cacc[mt][2][rg] + __uint_as_float(pb2));
            float p3 = ex2(cacc[mt][3][rg] + __uint_as_float(pb3));
            lpart[mt][rg] += (p0 + p1) + (p2 + p3);
            *(uint2*)((char*)Pb + pwoff[rg] + mt * 2048) =
                make_uint2(pk2bf(p0, p1), pk2bf(p2, p3));
        }

        // ---- PV GEMM (V fragments shared by both m-tiles) ----
        const char* pbW = (const char*)Pb + w * 4096;
#pragma unroll
        for (int kh = 0; kh < 2; kh++) {
            v8s vf[4];
#pragma unroll
            for (int nt = 0; nt < 4; nt++)
                vf[nt] = *(const v8s*)(vbase + kaddr[kh][nt]);
            v8s pa0 = *(const v8s*)(pbW + (paddr0 ^ (kh << 6)));
            v8s pa1 = *(const v8s*)(pbW + 2048 + (paddr0 ^ (kh << 6)));
            __builtin_amdgcn_s_setprio(1);
#pragma unroll
            for (int nt = 0; nt < 4; nt++)
                o_acc[0][nt] = __builtin_amdgcn_mfma_f32_16x16x32_bf16(
                    pa0, vf[nt], o_acc[0][nt], 0, 0, 0);
#pragma unroll
            for (int nt = 0; nt < 4; nt++)
                o_acc[1][nt] = __builtin_amdgcn_mfma_f32_16x16x32_bf16(
                    pa1, vf[nt], o_acc[1][nt], 0, 0, 0);
            __builtin_amdgcn_s_setprio(0);
        }
    }

    // ---- epilogue: row-sum reductions, then normalized stores ----
#pragma unroll
    for (int mt = 0; mt < 2; mt++)
#pragma unroll
    for (int rg = 0; rg < 4; rg++) {
        float rs = lpart[mt][rg];
#pragma unroll
        for (int off = 1; off < 16; off <<= 1)
            rs += __shfl_xor(rs, off);
        const float inv = 1.f / rs;
        const int row = s0 + i0 + mt * 16 + quad * 4 + rg;
        const size_t base = ((size_t)b * SEQ + row) * CH + h * HD;
#pragma unroll
        for (int nt = 0; nt < 4; nt++)
            out[base + nt * 16 + l15] = o_acc[mt][nt][rg] * inv;
    }
}

// ---------------------------------------------------------------------------
extern "C" void kernel_launch(void* const* d_in, const int* in_sizes, int n_in,
                              void* d_out, int out_size, void* d_ws, size_t ws_size,
                              hipStream_t stream)
{
    const float* src  = (const float*)d_in[0];
    const float* Wq   = (const float*)d_in[1];
    const float* bq   = (const float*)d_in[2];
    const float* Wk   = (const float*)d_in[3];
    const float* bk   = (const float*)d_in[4];
    const float* Wv   = (const float*)d_in[5];
    const float* bv   = (const float*)d_in[6];
    const float* relk = (const float*)d_in[7];
    float* out = (float*)d_out;

    const size_t nQKV = (size_t)BATCH * SEQ * CH;      // 4 Mi elements
    const size_t nW   = (size_t)CH * CH;               // 1 Mi
    short* qb   = (short*)d_ws;
    short* kb   = qb + nQKV;
    short* vb   = kb + nQKV;
    short* vtb  = vb + nQKV;
    short* xb   = vtb + nQKV;
    short* wqb  = xb + nQKV;
    short* wkb  = wqb + nW;
    short* wvb  = wkb + nW;
    short* relb = wvb + nW;                            // 4095*64 bf16

    cast_all_kernel<<<dim3(512, 1, 5), 256, 0, stream>>>(
        src, Wq, Wk, Wv, relk, xb, wqb, wkb, wvb, relb);

    dim3 gProj(4096 / 128, 1024 / 128, 3);             // (32, 8, 3): x = m-panel
    proj_mfma_kernel<<<gProj, 256, 0, stream>>>(
        xb, wqb, wkb, wvb, bq, bk, bv, qb, kb, vb);

    dim3 gVt(SEQ / 64, BHN);                           // (32, 32)
    vtrans_kernel<<<gVt, 256, 0, stream>>>(vb, vtb);

    dim3 gAttn(BHN, SEQ / 128);                        // (32, 16): x = bh
    attn_mfma_kernel<<<gAttn, 256, 0, stream>>>(qb, kb, vtb, relb, out);
}

// Round 4
// 208.682 us; speedup vs baseline: 1.4310x; 1.0038x over previous
//
#include <hip/hip_runtime.h>
#include <hip/hip_bf16.h>

#define BATCH 2
#define SEQ   2048
#define CH    1024
#define NH    16
#define HD    64
#define BHN   (BATCH*NH)   /* 32 */
#define SD    (SEQ*HD)     /* 131072 */

typedef short v8s __attribute__((ext_vector_type(8)));
typedef short v4s __attribute__((ext_vector_type(4)));
typedef float v4f __attribute__((ext_vector_type(4)));

__device__ __forceinline__ short f2bf(float f) {
    unsigned u = __float_as_uint(f);
    u += 0x7fff + ((u >> 16) & 1);   // RNE; finite inputs
    return (short)(u >> 16);
}

// packed RNE: returns (bf16(a) | bf16(b)<<16) via v_cvt_pk_bf16_f32
__device__ __forceinline__ unsigned pk2bf(float a, float b) {
    __hip_bfloat162 h = __float22bfloat162_rn(make_float2(a, b));
    unsigned u;
    __builtin_memcpy(&u, &h, 4);
    return u;
}

// v_exp_f32 IS exp2 on AMDGCN (scores are pre-scaled by log2e in proj)
__device__ __forceinline__ float ex2(float x) {
    float r; asm("v_exp_f32 %0, %1" : "=v"(r) : "v"(x)); return r;
}

#if __has_builtin(__builtin_amdgcn_perm)
#define PERMB(a, b, s) __builtin_amdgcn_perm((a), (b), (s))
#else
__device__ __forceinline__ unsigned PERMB(unsigned a, unsigned b, unsigned s) {
    unsigned r = 0;
#pragma unroll
    for (int i = 0; i < 4; i++) {
        unsigned sb = (s >> (8 * i)) & 0xff, byte;
        if (sb >= 12) byte = (sb == 12) ? 0u : 0xffu;
        else if (sb < 4) byte = (b >> (8 * sb)) & 0xff;
        else byte = (a >> (8 * (sb - 4))) & 0xff;
        r |= byte << (8 * i);
    }
    return r;
}
#endif

__device__ __forceinline__ void gl_lds16(const short* g, short* l) {
    __builtin_amdgcn_global_load_lds(
        (const __attribute__((address_space(1))) void*)g,
        (__attribute__((address_space(3))) void*)l, 16, 0, 0);
}

// ---------------------------------------------------------------------------
// Fused fp32 -> bf16 cast for src / Wq / Wk / Wv / rel_k_table.
// ---------------------------------------------------------------------------
__global__ __launch_bounds__(256) void cast_all_kernel(
    const float* __restrict__ src, const float* __restrict__ wq,
    const float* __restrict__ wk, const float* __restrict__ wv,
    const float* __restrict__ rel,
    short* __restrict__ xb, short* __restrict__ wqb,
    short* __restrict__ wkb, short* __restrict__ wvb,
    short* __restrict__ relb)
{
    const int z = blockIdx.z;
    const float* s; short* d; int n4;
    switch (z) {
        case 0: s = src; d = xb;   n4 = 1048576; break;  // 4Mi elems
        case 1: s = wq;  d = wqb;  n4 = 262144;  break;
        case 2: s = wk;  d = wkb;  n4 = 262144;  break;
        case 3: s = wv;  d = wvb;  n4 = 262144;  break;
        default: s = rel; d = relb; n4 = 65520;  break;  // 4095*64/4
    }
    for (int i = blockIdx.x * 256 + threadIdx.x; i < n4; i += gridDim.x * 256) {
        float4 v = ((const float4*)s)[i];
        v4s o; o.x = f2bf(v.x); o.y = f2bf(v.y); o.z = f2bf(v.z); o.w = f2bf(v.w);
        ((v4s*)d)[i] = o;
    }
}

// ---------------------------------------------------------------------------
// bf16 MFMA projection GEMM: out[m][n] = sum_k X[m][k]*W[n][k] + bias[n]
// M=4096, N=K=1024. 128x128 tile, BK=32, global_load_lds width 16.
// z==0 (Q): result pre-scaled by 0.125*log2e (attn uses raw exp2).
// ---------------------------------------------------------------------------
__global__ __launch_bounds__(256, 3) void proj_mfma_kernel(
    const short* __restrict__ Xb,
    const short* __restrict__ Wqb, const short* __restrict__ Wkb,
    const short* __restrict__ Wvb,
    const float* __restrict__ bq, const float* __restrict__ bk,
    const float* __restrict__ bv,
    short* __restrict__ qo, short* __restrict__ ko, short* __restrict__ vo)
{
    const int z = blockIdx.z;
    const short* W    = (z == 0) ? Wqb : (z == 1) ? Wkb : Wvb;
    const float* bias = (z == 0) ? bq  : (z == 1) ? bk  : bv;
    short*       out  = (z == 0) ? qo  : (z == 1) ? ko  : vo;
    const float  osc  = (z == 0) ? 0.125f * 1.44269504088896f : 1.0f;

    const int m0 = blockIdx.x * 128;
    const int n0 = blockIdx.y * 128;
    const int tid  = threadIdx.x;
    const int w    = tid >> 6;
    const int lane = tid & 63;
    const int l15  = lane & 15;
    const int quad = lane >> 4;
    const int wm = w & 1, wn = w >> 1;

    __shared__ short Al[128 * 32];   // [row][k], stride 32 (no pad: glds)
    __shared__ short Bl[128 * 32];

    v4f acc[4][4];
#pragma unroll
    for (int i = 0; i < 4; i++)
#pragma unroll
        for (int j = 0; j < 4; j++) acc[i][j] = (v4f)(0.f);

    const int lr = lane >> 2;          // 0..15 row-within-slab
    const int lc = (lane & 3) * 8;     // k-offset

    for (int k0 = 0; k0 < 1024; k0 += 32) {
        __syncthreads();
#pragma unroll
        for (int l = 0; l < 2; l++) {
            const int slab = w * 32 + l * 16;
            gl_lds16(Xb + (size_t)(m0 + slab + lr) * 1024 + k0 + lc,
                     &Al[slab * 32]);
            gl_lds16(W + (size_t)(n0 + slab + lr) * 1024 + k0 + lc,
                     &Bl[slab * 32]);
        }
        __syncthreads();
        v8s af[4], bf[4];
#pragma unroll
        for (int mt = 0; mt < 4; mt++)
            af[mt] = *(const v8s*)&Al[(wm * 64 + mt * 16 + l15) * 32 + quad * 8];
#pragma unroll
        for (int nt = 0; nt < 4; nt++)
            bf[nt] = *(const v8s*)&Bl[(wn * 64 + nt * 16 + l15) * 32 + quad * 8];
#pragma unroll
        for (int mt = 0; mt < 4; mt++)
#pragma unroll
            for (int nt = 0; nt < 4; nt++)
                acc[mt][nt] = __builtin_amdgcn_mfma_f32_16x16x32_bf16(
                    af[mt], bf[nt], acc[mt][nt], 0, 0, 0);
    }

    float bv4[4];
#pragma unroll
    for (int nt = 0; nt < 4; nt++)
        bv4[nt] = bias[n0 + wn * 64 + nt * 16 + l15];
#pragma unroll
    for (int mt = 0; mt < 4; mt++)
#pragma unroll
        for (int rg = 0; rg < 4; rg++) {
            const int row = m0 + wm * 64 + mt * 16 + quad * 4 + rg;
#pragma unroll
            for (int nt = 0; nt < 4; nt++)
                out[(size_t)row * 1024 + n0 + wn * 64 + nt * 16 + l15] =
                    f2bf((acc[mt][nt][rg] + bv4[nt]) * osc);
        }
}

// ---------------------------------------------------------------------------
// V transpose per (b,h): vt[bh][d][.] = v[bh][.][d].  64x64 LDS tiles.
// Columns within each 64-wide t-group are stored PERMUTED:
//   position p holds t(p) = (p>>2) + 16*(p&3)   (inverse: p = (t&15)*4 + t>>4)
// so the attention kernel's P-tile can be written with packed b64 stores.
// ---------------------------------------------------------------------------
__global__ __launch_bounds__(256) void vtrans_kernel(
    const short* __restrict__ v, short* __restrict__ vt)
{
    const int bh = blockIdx.y;
    const int t0 = blockIdx.x * 64;
    const int r = threadIdx.x >> 3;          // 0..31
    const int c = (threadIdx.x & 7) * 8;     // 0..56

    __shared__ short T[64][72];
    *(v8s*)&T[r][c] =
        *(const v8s*)(v + (size_t)bh * SD + (size_t)(t0 + r) * HD + c);
    *(v8s*)&T[r + 32][c] =
        *(const v8s*)(v + (size_t)bh * SD + (size_t)(t0 + r + 32) * HD + c);
    __syncthreads();
    v8s o0, o1;
#pragma unroll
    for (int e = 0; e < 8; e++) {
        const int t = 2 * (threadIdx.x & 7) + (e >> 2) + 16 * (e & 3);
        o0[e] = T[t][r];
        o1[e] = T[t][r + 32];
    }
    *(v8s*)(vt + (size_t)bh * SD + (size_t)r * SEQ + t0 + c) = o0;
    *(v8s*)(vt + (size_t)bh * SD + (size_t)(r + 32) * SEQ + t0 + c) = o1;
}

// ---------------------------------------------------------------------------
// MFMA flash attention with relative-position scores (bf16 inputs; q tensor
// pre-scaled by log2e/8 in the projection; probabilities via raw v_exp_f32).
//   score[i][t]*log2e = qs[i]·k[t] + qrs[i]·rel[t-i+2047]
//
// R14: 1-tile-delayed PV software pipeline (T15 att[2] style). R13 counters
// showed waves ~70% stalled (2 waves/SIMD, long serial chain per iter).
// PV[t-1] is independent of softmax[t], so per iteration:
//   B1 -> stage K[t+1]+rel -> QK[t] (MFMA) -> PHASE1[t] (pack+bpermute)
//   -> PV[t-1] (MFMA; Pb from last iter, V[t-1] in dbuf[cur^1])
//   -> B2 -> stage V[t+1] into dbuf[cur^1] -> PHASE2[t] (perm+exp+Pb write)
// PV MFMAs fill the bpermute-latency window; QK MFMA latency hides under PV.
// B2 makes the V-buffer handoff race-free (all waves' V reads precede it);
// its vmcnt drain is cheap (K/rel issued ~1400cyc earlier). V[t+1] gets
// PHASE2 (~500cyc) of latency cover.
// LDS: 16K(K) + 16K(V) + 32K(rel ring) + 16K(Pb) = 80 KB -> 2 blocks/CU.
// ---------------------------------------------------------------------------
__global__ __launch_bounds__(256, 2) void attn_mfma_kernel(
    const short* __restrict__ qb, const short* __restrict__ kb,
    const short* __restrict__ vtb, const short* __restrict__ relb,
    float* __restrict__ out)
{
    const int tid  = threadIdx.x;
    const int w    = tid >> 6;               // 0..3
    const int lane = tid & 63;
    const int l15  = lane & 15;
    const int quad = lane >> 4;
    const int bh = blockIdx.x, b = bh >> 4, h = bh & 15;
    const int s0 = blockIdx.y * 128;
    const int i0 = w * 32;                   // wave's 32-row slab

    __shared__ short Kl[2][64][64];      // key tile, dbuf, XOR-swizzled
    __shared__ short Vl[2][64][64];      // V^T tile, dbuf, XOR-swizzled (+perm cols)
    __shared__ short Rl[256][64];        // rel ring, XOR-swizzled
    __shared__ short Pb[4][2][16][64];   // per-wave/mt P (bf16, perm cols, swz)

    // ---- loop-invariant q fragments (both views, both m-tiles) ----
    v8s qc_f[2][2], qr_f[2][2];
#pragma unroll
    for (int mt = 0; mt < 2; mt++)
#pragma unroll
    for (int kh = 0; kh < 2; kh++) {
        const int row = s0 + i0 + mt * 16 + l15;
        qc_f[mt][kh] = *(const v8s*)(qb + (size_t)bh * SD +
                                     (size_t)row * HD + kh * 32 + quad * 8);
        qr_f[mt][kh] = *(const v8s*)(qb + (size_t)row * (BHN * HD) +
                                     bh * HD + kh * 32 + quad * 8);
    }

    // ---- loop-invariant gather selectors (v_perm; 0x0c = zero byte) ----
    int      slv4[4];
    unsigned selA[4], selB[4], pwoff[4];
#pragma unroll
    for (int rg = 0; rg < 4; rg++) {
        const int ii = quad * 4 + rg;
        const int e  = l15 + 15 - ii;          // [0,30]
        const bool lo = (e < 16);
        slv4[rg] = (quad * 16 + (e & 15)) << 2;
        selA[rg] = lo ? 0x05040c0cu : 0x07060c0cu;   // lo16<<16 : hi16
        selB[rg] = lo ? 0x07060c0cu : 0x01000c0cu;   // S0 hi16 : S1 lo16<<16
        pwoff[rg] = (unsigned)(w * 4096 + ii * 128 +
                    ((((l15 >> 1) ^ (ii & 7)) << 4) + ((l15 & 1) << 3)));
    }

    // ---- loop-invariant LDS read byte-offsets ----
    const int swz = (quad ^ (l15 & 7)) << 4;
    int kaddr[2][4];
#pragma unroll
    for (int kh = 0; kh < 2; kh++) {
        const int x = kh << 6;
#pragma unroll
        for (int nt = 0; nt < 4; nt++)
            kaddr[kh][nt] = (((nt * 16 + l15) << 7) + swz) ^ x;
    }
    const int paddr0 = (l15 << 7) + swz;       // within one 2KB Pb m-tile

    // ---- rel strip read byte-offsets (6 tiles; m1 uses 0..4, m0 uses 1..5) ----
    const int Bq = 1920 - s0;                  // min logical rel row for block
    int raddr[6];
#pragma unroll
    for (int st = 0; st < 6; st++) {
        const int lg = 2032 - s0 - i0 - 16 + st * 16 + l15;  // m1 frame @ t0=0
        raddr[st] = ((lg & 255) << 7) + ((quad ^ (lg & 7)) << 4);
    }

    // ---- staging geometry: 256 threads x2 issues cover one 64x64 tile ----
    const int strow = tid >> 3;                            // 0..31
    const int stc   = ((tid & 7) ^ (strow & 7)) * 8;       // swizzled src col
    const short* ksrc = kb  + (size_t)bh * SD + (size_t)strow * HD  + stc;
    const short* vsrc = vtb + (size_t)bh * SD + (size_t)strow * SEQ + stc;

    // ---- prologue staging: rel window [Bq, Bq+192) + K/V tile 0 ----
#pragma unroll
    for (int g = 0; g < 3; g++) {
        const int r0 = Bq + g * 64 + strow;
        const int ra = r0 < 4094 ? r0 : 4094;
        const int rb2 = (r0 + 32) < 4094 ? (r0 + 32) : 4094;
        const unsigned sl = (unsigned)((Bq + g * 64 + w * 8) & 255) << 7;
        gl_lds16(relb + (size_t)ra * HD + stc, (short*)((char*)Rl + sl));
        gl_lds16(relb + (size_t)rb2 * HD + stc, (short*)((char*)Rl + sl + 4096));
    }
    gl_lds16(ksrc,              &Kl[0][w * 8][0]);
    gl_lds16(ksrc + 32 * HD,    &Kl[0][32 + w * 8][0]);
    gl_lds16(vsrc,              &Vl[0][w * 8][0]);
    gl_lds16(vsrc + 32 * SEQ,   &Vl[0][32 + w * 8][0]);

    // ---- carried staging pointers ----
    const short* kp = ksrc + 4096;             // tile 1 (64 keys * HD)
    const short* vp = vsrc + 64;
    const char*  relbp = (const char*)relb + stc * 2;
    unsigned roff = (unsigned)(Bq + 192 + strow) * 128;  // byte row offset
    const unsigned ROMAX = 4094u * 128;
    unsigned rlds = (unsigned)((Bq + 192 + w * 8) & 255) << 7;

    v4f o_acc[2][4];
#pragma unroll
    for (int mt = 0; mt < 2; mt++)
#pragma unroll
        for (int nt = 0; nt < 4; nt++) o_acc[mt][nt] = (v4f)(0.f);
    float lpart[2][4] = {{0.f,0.f,0.f,0.f},{0.f,0.f,0.f,0.f}};

    // ---- pipeline state (shared by phase lambdas) ----
    v4f cacc[2][4], racc[2][5];
    unsigned g01[2][4], g23[2][4], g4v[2][4];

    auto ZACC = [&]() {
#pragma unroll
        for (int mt = 0; mt < 2; mt++) {
#pragma unroll
            for (int nt = 0; nt < 4; nt++) cacc[mt][nt] = (v4f)(0.f);
#pragma unroll
            for (int jt = 0; jt < 5; jt++) racc[mt][jt] = (v4f)(0.f);
        }
    };

    auto STAGE_K = [&](int dst) {            // K[next] + rel ring advance
        short* kd = &Kl[0][w * 8][0] + (dst << 12);
        gl_lds16(kp,            kd);
        gl_lds16(kp + 32 * HD,  kd + 32 * 64);
        unsigned rc0 = roff < ROMAX ? roff : ROMAX;
        unsigned rc1 = (roff + 4096) < ROMAX ? (roff + 4096) : ROMAX;
        gl_lds16((const short*)(relbp + rc0), (short*)((char*)Rl + rlds));
        gl_lds16((const short*)(relbp + rc1), (short*)((char*)Rl + rlds + 4096));
        kp += 4096; roff += 8192; rlds = (rlds + 8192) & 32767;
    };

    auto STAGE_V = [&](int dst) {            // V[next]
        short* vd = &Vl[0][w * 8][0] + (dst << 12);
        gl_lds16(vp,            vd);
        gl_lds16(vp + 32 * SEQ, vd + 32 * 64);
        vp += 64;
    };

    auto QK = [&](int cur) {
        const char* kbase = (const char*)Kl + cur * 8192;
        const char* rbase = (const char*)Rl;
#pragma unroll
        for (int kh = 0; kh < 2; kh++) {
            v8s kf[4], rfj[6];
#pragma unroll
            for (int nt = 0; nt < 4; nt++)
                kf[nt] = *(const v8s*)(kbase + kaddr[kh][nt]);
#pragma unroll
            for (int st = 0; st < 6; st++)
                rfj[st] = *(const v8s*)(rbase + (raddr[st] ^ (kh << 6)));
            __builtin_amdgcn_s_setprio(1);
#pragma unroll
            for (int mt = 0; mt < 2; mt++)
#pragma unroll
                for (int nt = 0; nt < 4; nt++)
                    cacc[mt][nt] = __builtin_amdgcn_mfma_f32_16x16x32_bf16(
                        qc_f[mt][kh], kf[nt], cacc[mt][nt], 0, 0, 0);
#pragma unroll
            for (int jt = 0; jt < 5; jt++)
                racc[0][jt] = __builtin_amdgcn_mfma_f32_16x16x32_bf16(
                    qr_f[0][kh], rfj[jt + 1], racc[0][jt], 0, 0, 0);
#pragma unroll
            for (int jt = 0; jt < 5; jt++)
                racc[1][jt] = __builtin_amdgcn_mfma_f32_16x16x32_bf16(
                    qr_f[1][kh], rfj[jt], racc[1][jt], 0, 0, 0);
            __builtin_amdgcn_s_setprio(0);
        }
#pragma unroll
        for (int st = 0; st < 6; st++) raddr[st] = (raddr[st] + 8192) & 32767;
    };

    auto PHASE1 = [&]() {                    // pack + 24 bpermutes
#pragma unroll
        for (int mt = 0; mt < 2; mt++)
#pragma unroll
        for (int rg = 0; rg < 4; rg++) {
            unsigned p01 = pk2bf(racc[mt][0][rg], racc[mt][1][rg]);
            unsigned p23 = pk2bf(racc[mt][2][rg], racc[mt][3][rg]);
            unsigned p4  = pk2bf(racc[mt][4][rg], racc[mt][4][rg]);
            g01[mt][rg] = (unsigned)__builtin_amdgcn_ds_bpermute(slv4[rg], (int)p01);
            g23[mt][rg] = (unsigned)__builtin_amdgcn_ds_bpermute(slv4[rg], (int)p23);
            g4v[mt][rg] = (unsigned)__builtin_amdgcn_ds_bpermute(slv4[rg], (int)p4);
        }
    };

    auto PHASE2 = [&]() {                    // skew-select + exp2 + Pb writes
#pragma unroll
        for (int mt = 0; mt < 2; mt++)
#pragma unroll
        for (int rg = 0; rg < 4; rg++) {
            const unsigned a01 = g01[mt][rg], a23 = g23[mt][rg], a4 = g4v[mt][rg];
            unsigned pb0 = PERMB(a01, a01, selA[rg]);
            unsigned pb1 = PERMB(a01, a23, selB[rg]);
            unsigned pb2 = PERMB(a23, a23, selA[rg]);
            unsigned pb3 = PERMB(a23, a4,  selB[rg]);
            float p0 = ex2(cacc[mt][0][rg] + __uint_as_float(pb0));
            float p1 = ex2(cacc[mt][1][rg] + __uint_as_float(pb1));
            float p2 = ex2(cacc[mt][2][rg] + __uint_as_float(pb2));
            float p3 = ex2(cacc[mt][3][rg] + __uint_as_float(pb3));
            lpart[mt][rg] += (p0 + p1) + (p2 + p3);
            *(uint2*)((char*)Pb + pwoff[rg] + mt * 2048) =
                make_uint2(pk2bf(p0, p1), pk2bf(p2, p3));
        }
    };

    auto PV = [&](int vbuf) {                // PV GEMM on delayed tile
        const char* vbase = (const char*)Vl + vbuf * 8192;
        const char* pbW = (const char*)Pb + w * 4096;
#pragma unroll
        for (int kh = 0; kh < 2; kh++) {
            v8s vf[4];
#pragma unroll
            for (int nt = 0; nt < 4; nt++)
                vf[nt] = *(const v8s*)(vbase + kaddr[kh][nt]);
            v8s pa0 = *(const v8s*)(pbW + (paddr0 ^ (kh << 6)));
            v8s pa1 = *(const v8s*)(pbW + 2048 + (paddr0 ^ (kh << 6)));
            __builtin_amdgcn_s_setprio(1);
#pragma unroll
            for (int nt = 0; nt < 4; nt++)
                o_acc[0][nt] = __builtin_amdgcn_mfma_f32_16x16x32_bf16(
                    pa0, vf[nt], o_acc[0][nt], 0, 0, 0);
#pragma unroll
            for (int nt = 0; nt < 4; nt++)
                o_acc[1][nt] = __builtin_amdgcn_mfma_f32_16x16x32_bf16(
                    pa1, vf[nt], o_acc[1][nt], 0, 0, 0);
            __builtin_amdgcn_s_setprio(0);
        }
    };

    // ================= prologue iteration (t0 = 0) =================
    __syncthreads();                 // K[0],V[0],rel[Bq..Bq+192) staged
    STAGE_K(1);
    STAGE_V(1);
    ZACC(); QK(0); PHASE1(); PHASE2();

    // ================= main loop (31 iterations) =================
    int cur = 0;
    for (int t0 = 64; t0 < SEQ; t0 += 64) {
        cur ^= 1;
        __syncthreads();             // B1: K[t],V[t],rel drained
        STAGE_K(cur ^ 1);            // K[t+1] (full-iter cover)
        ZACC(); QK(cur);
        PHASE1();
        PV(cur ^ 1);                 // PV[t-1]: V in dbuf[cur^1], P in Pb
        __syncthreads();             // B2: all PV reads done (cheap drain)
        STAGE_V(cur ^ 1);            // V[t+1]; PHASE2 covers its latency
        PHASE2();
    }
    PV(cur);                         // PV[last]: V[last] in dbuf[cur]

    // ---- epilogue: row-sum reductions, then normalized stores ----
#pragma unroll
    for (int mt = 0; mt < 2; mt++)
#pragma unroll
    for (int rg = 0; rg < 4; rg++) {
        float rs = lpart[mt][rg];
#pragma unroll
        for (int off = 1; off < 16; off <<= 1)
            rs += __shfl_xor(rs, off);
        const float inv = 1.f / rs;
        const int row = s0 + i0 + mt * 16 + quad * 4 + rg;
        const size_t base = ((size_t)b * SEQ + row) * CH + h * HD;
#pragma unroll
        for (int nt = 0; nt < 4; nt++)
            out[base + nt * 16 + l15] = o_acc[mt][nt][rg] * inv;
    }
}

// ---------------------------------------------------------------------------
extern "C" void kernel_launch(void* const* d_in, const int* in_sizes, int n_in,
                              void* d_out, int out_size, void* d_ws, size_t ws_size,
                              hipStream_t stream)
{
    const float* src  = (const float*)d_in[0];
    const float* Wq   = (const float*)d_in[1];
    const float* bq   = (const float*)d_in[2];
    const float* Wk   = (const float*)d_in[3];
    const float* bk   = (const float*)d_in[4];
    const float* Wv   = (const float*)d_in[5];
    const float* bv   = (const float*)d_in[6];
    const float* relk = (const float*)d_in[7];
    float* out = (float*)d_out;

    const size_t nQKV = (size_t)BATCH * SEQ * CH;      // 4 Mi elements
    const size_t nW   = (size_t)CH * CH;               // 1 Mi
    short* qb   = (short*)d_ws;
    short* kb   = qb + nQKV;
    short* vb   = kb + nQKV;
    short* vtb  = vb + nQKV;
    short* xb   = vtb + nQKV;
    short* wqb  = xb + nQKV;
    short* wkb  = wqb + nW;
    short* wvb  = wkb + nW;
    short* relb = wvb + nW;                            // 4095*64 bf16

    cast_all_kernel<<<dim3(512, 1, 5), 256, 0, stream>>>(
        src, Wq, Wk, Wv, relk, xb, wqb, wkb, wvb, relb);

    dim3 gProj(4096 / 128, 1024 / 128, 3);             // (32, 8, 3): x = m-panel
    proj_mfma_kernel<<<gProj, 256, 0, stream>>>(
        xb, wqb, wkb, wvb, bq, bk, bv, qb, kb, vb);

    dim3 gVt(SEQ / 64, BHN);                           // (32, 32)
    vtrans_kernel<<<gVt, 256, 0, stream>>>(vb, vtb);

    dim3 gAttn(BHN, SEQ / 128);                        // (32, 16): x = bh
    attn_mfma_kernel<<<gAttn, 256, 0, stream>>>(qb, kb, vtb, relb, out);
}